// Round 8
// baseline (3839.852 us; speedup 1.0000x reference)
//
#include <hip/hip_runtime.h>
#include <math.h>

#define B_   32
#define L_   512
#define E_   300
#define H_   256
#define T_   4
#define NTOK 16384  // B*L
#define XGLD 2048   // 2 directions * 4H
#define SENT 2.0f   // impossible h value: |h| = |sigm*tanh| < 1

typedef float f32x4 __attribute__((ext_vector_type(4)));

__device__ __forceinline__ float sigmoidf_(float x) { return 1.0f / (1.0f + expf(-x)); }

// LLC-coherent (agent-scope) vector ops: sc0 sc1 bypass L1/L2 like relaxed
// agent atomics, but vectorized. Caller must s_waitcnt vmcnt before using loads.
__device__ __forceinline__ void llc_store_f32(float* p, float v) {
  asm volatile("global_store_dword %0, %1, off sc0 sc1" :: "v"(p), "v"(v) : "memory");
}
__device__ __forceinline__ void llc_store_f32x4(float* p, f32x4 v) {
  asm volatile("global_store_dwordx4 %0, %1, off sc0 sc1" :: "v"(p), "v"(v) : "memory");
}
__device__ __forceinline__ f32x4 llc_load_f32x4(const float* p) {
  f32x4 r;
  asm volatile("global_load_dwordx4 %0, %1, off sc0 sc1" : "=&v"(r) : "v"(p) : "memory");
  return r;
}

// ---------- stage A: xg[row][d*1024+g] = emb[wid[row]] . Wih_d[g] + b_d[g] ----------
#define BM 64
#define BN 64
#define BK 20
__global__ __launch_bounds__(256) void xproj_kernel(
    const int*   __restrict__ wid,    // [NTOK]
    const float* __restrict__ emb,    // [V][300]
    const float* __restrict__ wih_f,  // [1024][300]
    const float* __restrict__ wih_b,
    const float* __restrict__ b_f,
    const float* __restrict__ b_b,
    float* __restrict__ xg)           // [NTOK][2048]
{
  __shared__ float As[BM][BK + 1];
  __shared__ float Bs[BK][BN];
  __shared__ int   wid_s[BM];

  int tid = threadIdx.x;
  int m0 = blockIdx.y * BM;
  int n0 = blockIdx.x * BN;            // global col 0..2047
  int d  = n0 >> 10;
  const float* wih  = d ? wih_b : wih_f;
  const float* bias = d ? b_b  : b_f;
  int g0 = n0 & 1023;

  if (tid < BM) wid_s[tid] = wid[m0 + tid];
  __syncthreads();

  int lm = tid >> 2;          // 0..63
  int lk = (tid & 3) * 5;     // 0,5,10,15
  int tx = tid & 15, ty = tid >> 4;

  float acc[4][4] = {};

  for (int k0 = 0; k0 < 300; k0 += BK) {
    const float* erow = emb + (size_t)wid_s[lm] * E_ + k0 + lk;
#pragma unroll
    for (int i = 0; i < 5; ++i) As[lm][lk + i] = erow[i];
    const float* wrow = wih + (size_t)(g0 + lm) * E_ + k0 + lk;
#pragma unroll
    for (int i = 0; i < 5; ++i) Bs[lk + i][lm] = wrow[i];
    __syncthreads();
#pragma unroll
    for (int k = 0; k < BK; ++k) {
      float a0 = As[ty * 4 + 0][k], a1 = As[ty * 4 + 1][k];
      float a2 = As[ty * 4 + 2][k], a3 = As[ty * 4 + 3][k];
      float b0 = Bs[k][tx * 4 + 0], b1 = Bs[k][tx * 4 + 1];
      float b2 = Bs[k][tx * 4 + 2], b3 = Bs[k][tx * 4 + 3];
      acc[0][0] += a0 * b0; acc[0][1] += a0 * b1; acc[0][2] += a0 * b2; acc[0][3] += a0 * b3;
      acc[1][0] += a1 * b0; acc[1][1] += a1 * b1; acc[1][2] += a1 * b2; acc[1][3] += a1 * b3;
      acc[2][0] += a2 * b0; acc[2][1] += a2 * b1; acc[2][2] += a2 * b2; acc[2][3] += a2 * b3;
      acc[3][0] += a3 * b0; acc[3][1] += a3 * b1; acc[3][2] += a3 * b2; acc[3][3] += a3 * b3;
    }
    __syncthreads();
  }

#pragma unroll
  for (int i = 0; i < 4; ++i) {
    int row = m0 + ty * 4 + i;
    float* op = xg + (size_t)row * XGLD + n0 + tx * 4;
#pragma unroll
    for (int jj = 0; jj < 4; ++jj)
      op[jj] = acc[i][jj] + bias[g0 + tx * 4 + jj];
  }
}

// ---------- sentinel fill for h_all (replay-safe, runs every launch) ----------
__global__ __launch_bounds__(256) void fill_sentinel(float* p, int n4) {
  int i = blockIdx.x * 256 + threadIdx.x;
  if (i < n4) {
    f32x4 v = {SENT, SENT, SENT, SENT};
    llc_store_f32x4(p + (size_t)i * 4, v);
  }
}

// ---------- stage B: LSTM, two-phase batch pipeline hiding LLC sync ----------
// Block = (d, slice sl of 16 units). Each block advances BOTH batch-halves:
//   GEMM A(s) -> publish A(s) -> spin B(s-1) -> GEMM B(s) -> publish B(s) -> spin A(s)
// Every spin target was published ~1 phase of compute earlier by partners, so the
// LLC round-trip hides under the other half's GEMM. Sentinel-data sync, no flags.
__global__ __launch_bounds__(512, 1) void lstm_kernel(
    const float* __restrict__ xg,     // [NTOK][2048]
    const float* __restrict__ whh_f,  // [1024][256]
    const float* __restrict__ whh_b,  // [1024][256]
    float*       h_all)               // [4 grp][512 t][256 j][16 bl]
{
  const int bid = blockIdx.x;        // 0..31
  const int d   = bid >> 4;
  const int sl  = bid & 15;
  const int tid = threadIdx.x;
  const int kp  = tid >> 6;          // 0..7 (wave id)
  const int cg  = (tid >> 4) & 3;    // batch quad
  const int rg  = tid & 15;          // row quad
  const float* __restrict__ whh = d ? whh_b : whh_f;

  __shared__ float w_lds[256 * 64];        // w_t[k][row], row = gt*16+u   (64 KB)
  __shared__ float hA_lds[256 * 20];       // h_t[k][bl+pad] batches 0..15 (20 KB)
  __shared__ float hB_lds[256 * 20];       // batches 16..31               (20 KB)
  __shared__ float part_lds[8 * 16 * 68];  // part[kp][bl][row+pad]        (34.8 KB)

  // ---- load + transpose weight slice into LDS (once) ----
  {
    const int row_l = tid & 63;            // gt*16 + u
    const int kq    = tid >> 6;            // 0..7, 32 k each
    const int grow  = (row_l >> 4) * 256 + sl * 16 + (row_l & 15);
    const float* src = whh + (size_t)grow * H_ + kq * 32;
#pragma unroll
    for (int i = 0; i < 8; ++i) {
      f32x4 v = *(const f32x4*)(src + i * 4);
      const int kb = kq * 32 + i * 4;
      w_lds[(kb + 0) * 64 + row_l] = v.x;
      w_lds[(kb + 1) * 64 + row_l] = v.y;
      w_lds[(kb + 2) * 64 + row_l] = v.z;
      w_lds[(kb + 3) * 64 + row_l] = v.w;
    }
  }
  for (int idx = tid; idx < 256 * 20; idx += 512) { hA_lds[idx] = 0.f; hB_lds[idx] = 0.f; }
  __syncthreads();

  float cA = 0.f, cB = 0.f;
  float* hgrpA = h_all + (size_t)(d * 2 + 0) * (L_ * 4096);  // [512][256][16]
  float* hgrpB = h_all + (size_t)(d * 2 + 1) * (L_ * 4096);

  const int u_r  = tid >> 4;   // reduce-phase unit (tid<256)
  const int bl_r = tid & 15;   // reduce-phase batch-in-half
  const int kbase = kp * 32;

  // xg prefetch registers (tid<256): A = batch bl_r, B = batch 16+bl_r
  const float* xbaseA = xg + ((size_t)bl_r * L_) * XGLD + d * 1024 + sl * 16 + u_r;
  const float* xbaseB = xg + ((size_t)(16 + bl_r) * L_) * XGLD + d * 1024 + sl * 16 + u_r;
  float xA0 = 0.f, xA1 = 0.f, xA2 = 0.f, xA3 = 0.f;
  float xB0 = 0.f, xB1 = 0.f, xB2 = 0.f, xB3 = 0.f;
  if (tid < 256) {
    const int t0 = d ? (L_ - 1) : 0;
    const float* pa = xbaseA + (size_t)t0 * XGLD;
    const float* pb = xbaseB + (size_t)t0 * XGLD;
    xA0 = pa[0]; xA1 = pa[256]; xA2 = pa[512]; xA3 = pa[768];
    xB0 = pb[0]; xB1 = pb[256]; xB2 = pb[512]; xB3 = pb[768];
  }

#define GEMM_PHASE(HLDS)                                                      \
  do {                                                                        \
    float acc[4][4] = {};                                                     \
    _Pragma("unroll 8")                                                       \
    for (int i = 0; i < 32; ++i) {                                            \
      const int k = kbase + i;                                                \
      f32x4 wv = *(const f32x4*)&w_lds[k * 64 + rg * 4];                      \
      f32x4 hv = *(const f32x4*)&HLDS[k * 20 + cg * 4];                       \
      acc[0][0] += wv.x * hv.x; acc[0][1] += wv.x * hv.y;                     \
      acc[0][2] += wv.x * hv.z; acc[0][3] += wv.x * hv.w;                     \
      acc[1][0] += wv.y * hv.x; acc[1][1] += wv.y * hv.y;                     \
      acc[1][2] += wv.y * hv.z; acc[1][3] += wv.y * hv.w;                     \
      acc[2][0] += wv.z * hv.x; acc[2][1] += wv.z * hv.y;                     \
      acc[2][2] += wv.z * hv.z; acc[2][3] += wv.z * hv.w;                     \
      acc[3][0] += wv.w * hv.x; acc[3][1] += wv.w * hv.y;                     \
      acc[3][2] += wv.w * hv.z; acc[3][3] += wv.w * hv.w;                     \
    }                                                                         \
    _Pragma("unroll")                                                         \
    for (int cc = 0; cc < 4; ++cc) {                                          \
      f32x4 pv = {acc[0][cc], acc[1][cc], acc[2][cc], acc[3][cc]};            \
      *(f32x4*)&part_lds[kp * 1088 + (cg * 4 + cc) * 68 + rg * 4] = pv;       \
    }                                                                         \
  } while (0)

#define REDUCE_PUBLISH(CVAR, X0, X1, X2, X3, HGRP)                            \
  do {                                                                        \
    if (tid < 256) {                                                          \
      float g0 = X0, g1 = X1, g2 = X2, g3 = X3;                               \
      _Pragma("unroll")                                                       \
      for (int k2 = 0; k2 < 8; ++k2) {                                        \
        const float* pp = &part_lds[k2 * 1088 + bl_r * 68 + u_r];             \
        g0 += pp[0]; g1 += pp[16]; g2 += pp[32]; g3 += pp[48];                \
      }                                                                       \
      float gi = sigmoidf_(g0);                                               \
      float gf = sigmoidf_(g1);                                               \
      float gg = tanhf(g2);                                                   \
      float go = sigmoidf_(g3);                                               \
      CVAR = gf * CVAR + gi * gg;                                             \
      float h = go * tanhf(CVAR);                                             \
      llc_store_f32(&HGRP[((size_t)t * 256 + sl * 16 + u_r) * 16 + bl_r], h); \
    }                                                                         \
  } while (0)

#define SPIN_LOAD(HGRP, HLDS, TT)                                             \
  do {                                                                        \
    const float* hsrc = HGRP + (size_t)(TT) * 4096;                           \
    const int j0 = tid >> 2, bq = tid & 3;                                    \
    const float* p0 = hsrc + j0 * 16 + bq * 4;                                \
    const float* p1 = p0 + 128 * 16;                                          \
    f32x4 v0, v1;                                                             \
    bool bad;                                                                 \
    do {                                                                      \
      v0 = llc_load_f32x4(p0);                                                \
      v1 = llc_load_f32x4(p1);                                                \
      asm volatile("s_waitcnt vmcnt(0)" ::: "memory");                        \
      __builtin_amdgcn_sched_barrier(0);                                      \
      bad = (v0.x == SENT) | (v0.y == SENT) | (v0.z == SENT) | (v0.w == SENT) |\
            (v1.x == SENT) | (v1.y == SENT) | (v1.z == SENT) | (v1.w == SENT);\
    } while (bad);                                                            \
    *(f32x4*)&HLDS[j0 * 20 + bq * 4] = v0;                                    \
    *(f32x4*)&HLDS[(j0 + 128) * 20 + bq * 4] = v1;                            \
  } while (0)

  for (int s = 0; s < L_; ++s) {
    const int t = d ? (L_ - 1 - s) : s;
    const int tn = d ? (L_ - 2 - s) : (s + 1);   // valid when s < L_-1

    // ===== phase A (batches 0..15) =====
    GEMM_PHASE(hA_lds);
    __syncthreads();
    REDUCE_PUBLISH(cA, xA0, xA1, xA2, xA3, hgrpA);
    if (s < L_ - 1 && tid < 256) {               // prefetch next xg(A)
      const float* pa = xbaseA + (size_t)tn * XGLD;
      xA0 = pa[0]; xA1 = pa[256]; xA2 = pa[512]; xA3 = pa[768];
    }
    if (s > 0) SPIN_LOAD(hgrpB, hB_lds, d ? (L_ - s) : (s - 1));
    __syncthreads();   // part reuse + hB_lds ready

    // ===== phase B (batches 16..31) =====
    GEMM_PHASE(hB_lds);
    __syncthreads();
    REDUCE_PUBLISH(cB, xB0, xB1, xB2, xB3, hgrpB);
    if (s < L_ - 1 && tid < 256) {               // prefetch next xg(B)
      const float* pb = xbaseB + (size_t)tn * XGLD;
      xB0 = pb[0]; xB1 = pb[256]; xB2 = pb[512]; xB3 = pb[768];
    }
    if (s == L_ - 1) break;
    SPIN_LOAD(hgrpA, hA_lds, t);
    __syncthreads();   // part reuse + hA_lds ready
  }

#undef GEMM_PHASE
#undef REDUCE_PUBLISH
#undef SPIN_LOAD
}

// ---------- emissions: per (t, bh) tile, em[b][t][tag] = bout + h_f.Wf + h_b.Wb ------
__global__ __launch_bounds__(256) void emis_kernel(
    const float* __restrict__ h_all,  // [4][512][256][16]
    const float* __restrict__ wout,   // [4][512]
    const float* __restrict__ bout,   // [4]
    float* __restrict__ em)           // [32][512][4]
{
  __shared__ float hf_l[4096];   // [j][bl]
  __shared__ float hb_l[4096];
  __shared__ float wsl[2048];
  __shared__ float red[256];

  const int t  = blockIdx.x >> 1;
  const int bh = blockIdx.x & 1;
  const int tid = threadIdx.x;
  const float* hfp = h_all + ((size_t)(0 + bh) * L_ + t) * 4096;
  const float* hbp = h_all + ((size_t)(2 + bh) * L_ + t) * 4096;

  for (int i = tid; i < 1024; i += 256) {
    *(f32x4*)&hf_l[i * 4] = *(const f32x4*)&hfp[i * 4];
    *(f32x4*)&hb_l[i * 4] = *(const f32x4*)&hbp[i * 4];
  }
  for (int i = tid; i < 2048; i += 256) wsl[i] = wout[i];
  __syncthreads();

  const int bl = tid & 15, tag = (tid >> 4) & 3, ch = tid >> 6;
  float s = 0.f;
#pragma unroll 8
  for (int jj = 0; jj < 64; ++jj) {
    const int j = ch * 64 + jj;
    s += hf_l[j * 16 + bl] * wsl[tag * 512 + j]
       + hb_l[j * 16 + bl] * wsl[tag * 512 + 256 + j];
  }
  red[tid] = s;
  __syncthreads();
  if (tid < 64) {
    const int tg = tid >> 4, bb = tid & 15;
    float v = red[tid] + red[tid + 64] + red[tid + 128] + red[tid + 192];
    em[((size_t)(bh * 16 + bb) * L_ + t) * 4 + tg] = v + bout[tg];
  }
}

// ---------- Viterbi decode: one block per batch, em/hist staged in LDS ----------
__global__ __launch_bounds__(64) void viterbi_kernel(
    const float* __restrict__ em,      // [32][512][4]  (bias included)
    const float* __restrict__ trans,   // [4][4]
    const float* __restrict__ strans,  // [4]
    const float* __restrict__ etrans,  // [4]
    const int*   __restrict__ mask,    // [32][512]
    int* __restrict__ out)             // [32][512]
{
  __shared__ float em_l[512 * 4];
  __shared__ int   msk_l[512];
  __shared__ int   hist_l[512 * 4];
  __shared__ int   tags_l[512];

  const int b = blockIdx.x;
  const int tid = threadIdx.x;
  const float* ep = em + (size_t)b * L_ * 4;

  for (int i = tid; i < 512; i += 64) {
    *(f32x4*)&em_l[i * 4] = *(const f32x4*)&ep[i * 4];
    msk_l[i] = mask[b * L_ + i];
  }
  __syncthreads();

  if (tid == 0) {
    float tr[4][4];
#pragma unroll
    for (int i = 0; i < 4; ++i)
#pragma unroll
      for (int jj = 0; jj < 4; ++jj) tr[i][jj] = trans[i * 4 + jj];

    float sc[4];
#pragma unroll
    for (int tag = 0; tag < 4; ++tag) sc[tag] = strans[tag] + em_l[tag];

    for (int t = 1; t < L_; ++t) {
      float ns[4];
#pragma unroll
      for (int to = 0; to < 4; ++to) {
        float best = sc[0] + tr[0][to];
        int bf = 0;
#pragma unroll
        for (int fr = 1; fr < 4; ++fr) {
          float v = sc[fr] + tr[fr][to];
          if (v > best) { best = v; bf = fr; }
        }
        ns[to] = best + em_l[t * 4 + to];
        hist_l[t * 4 + to] = bf;
      }
      const int mt = msk_l[t];
#pragma unroll
      for (int to = 0; to < 4; ++to) sc[to] = mt ? ns[to] : sc[to];
    }

#pragma unroll
    for (int tag = 0; tag < 4; ++tag) sc[tag] += etrans[tag];
    int cur = 0;
    float best = sc[0];
#pragma unroll
    for (int i = 1; i < 4; ++i)
      if (sc[i] > best) { best = sc[i]; cur = i; }

    tags_l[L_ - 1] = msk_l[L_ - 1] ? cur : 0;
    for (int t = L_ - 1; t >= 1; --t) {
      if (msk_l[t]) cur = hist_l[t * 4 + cur];
      tags_l[t - 1] = msk_l[t - 1] ? cur : 0;
    }
  }
  __syncthreads();
  for (int i = tid; i < 512; i += 64) out[b * L_ + i] = tags_l[i];
}

extern "C" void kernel_launch(void* const* d_in, const int* in_sizes, int n_in,
                              void* d_out, int out_size, void* d_ws, size_t ws_size,
                              hipStream_t stream) {
  const int*   word_ids = (const int*)d_in[0];
  const int*   mask     = (const int*)d_in[1];
  // d_in[2] label_ids: unused
  const float* emb   = (const float*)d_in[3];
  const float* Wih_f = (const float*)d_in[4];
  const float* Whh_f = (const float*)d_in[5];
  const float* b_f   = (const float*)d_in[6];
  const float* Wih_b = (const float*)d_in[7];
  const float* Whh_b = (const float*)d_in[8];
  const float* b_b   = (const float*)d_in[9];
  const float* W_out = (const float*)d_in[10];
  const float* b_out = (const float*)d_in[11];
  const float* trans = (const float*)d_in[12];
  const float* strans = (const float*)d_in[13];
  const float* etrans = (const float*)d_in[14];
  int* out = (int*)d_out;

  float* xg    = (float*)d_ws;                             // 128 MiB
  float* h_all = xg + (size_t)NTOK * XGLD;                 // 4*512*4096 f32 = 32 MiB
  float* em    = h_all + (size_t)4 * L_ * 4096;            // 256 KiB

  const int n4 = 4 * L_ * 4096 / 4;                        // 2,097,152 f32x4
  fill_sentinel<<<(n4 + 255) / 256, 256, 0, stream>>>(h_all, n4);
  xproj_kernel<<<dim3(32, 256), 256, 0, stream>>>(word_ids, emb, Wih_f, Wih_b, b_f, b_b, xg);
  lstm_kernel<<<32, 512, 0, stream>>>(xg, Whh_f, Whh_b, h_all);
  emis_kernel<<<1024, 256, 0, stream>>>(h_all, W_out, b_out, em);
  viterbi_kernel<<<32, 64, 0, stream>>>(em, trans, strans, etrans, mask, out);
}

// Round 9
// 1995.169 us; speedup vs baseline: 1.9246x; 1.9246x over previous
//
#include <hip/hip_runtime.h>
#include <math.h>

#define B_   32
#define L_   512
#define E_   300
#define H_   256
#define T_   4
#define NTOK 16384  // B*L
#define XGLD 2048   // 2 directions * 4H
#define SENT 2.0f   // impossible h value: |h| = |sigm*tanh| < 1

typedef float f32x4 __attribute__((ext_vector_type(4)));

__device__ __forceinline__ float sigmoidf_(float x) { return 1.0f / (1.0f + expf(-x)); }

// LLC-coherent (agent-scope) vector ops: sc0 sc1 bypass L1/L2 like relaxed
// agent atomics, but vectorized. Caller must s_waitcnt vmcnt before using loads.
__device__ __forceinline__ void llc_store_f32(float* p, float v) {
  asm volatile("global_store_dword %0, %1, off sc0 sc1" :: "v"(p), "v"(v) : "memory");
}
__device__ __forceinline__ void llc_store_f32x4(float* p, f32x4 v) {
  asm volatile("global_store_dwordx4 %0, %1, off sc0 sc1" :: "v"(p), "v"(v) : "memory");
}
__device__ __forceinline__ f32x4 llc_load_f32x4(const float* p) {
  f32x4 r;
  asm volatile("global_load_dwordx4 %0, %1, off sc0 sc1" : "=&v"(r) : "v"(p) : "memory");
  return r;
}

// ---------- stage A: xg[row][d*1024+g] = emb[wid[row]] . Wih_d[g] + b_d[g] ----------
#define BM 64
#define BN 64
#define BK 20
__global__ __launch_bounds__(256) void xproj_kernel(
    const int*   __restrict__ wid,    // [NTOK]
    const float* __restrict__ emb,    // [V][300]
    const float* __restrict__ wih_f,  // [1024][300]
    const float* __restrict__ wih_b,
    const float* __restrict__ b_f,
    const float* __restrict__ b_b,
    float* __restrict__ xg)           // [NTOK][2048]
{
  __shared__ float As[BM][BK + 1];
  __shared__ float Bs[BK][BN];
  __shared__ int   wid_s[BM];

  int tid = threadIdx.x;
  int m0 = blockIdx.y * BM;
  int n0 = blockIdx.x * BN;            // global col 0..2047
  int d  = n0 >> 10;
  const float* wih  = d ? wih_b : wih_f;
  const float* bias = d ? b_b  : b_f;
  int g0 = n0 & 1023;

  if (tid < BM) wid_s[tid] = wid[m0 + tid];
  __syncthreads();

  int lm = tid >> 2;          // 0..63
  int lk = (tid & 3) * 5;     // 0,5,10,15
  int tx = tid & 15, ty = tid >> 4;

  float acc[4][4] = {};

  for (int k0 = 0; k0 < 300; k0 += BK) {
    const float* erow = emb + (size_t)wid_s[lm] * E_ + k0 + lk;
#pragma unroll
    for (int i = 0; i < 5; ++i) As[lm][lk + i] = erow[i];
    const float* wrow = wih + (size_t)(g0 + lm) * E_ + k0 + lk;
#pragma unroll
    for (int i = 0; i < 5; ++i) Bs[lk + i][lm] = wrow[i];
    __syncthreads();
#pragma unroll
    for (int k = 0; k < BK; ++k) {
      float a0 = As[ty * 4 + 0][k], a1 = As[ty * 4 + 1][k];
      float a2 = As[ty * 4 + 2][k], a3 = As[ty * 4 + 3][k];
      float b0 = Bs[k][tx * 4 + 0], b1 = Bs[k][tx * 4 + 1];
      float b2 = Bs[k][tx * 4 + 2], b3 = Bs[k][tx * 4 + 3];
      acc[0][0] += a0 * b0; acc[0][1] += a0 * b1; acc[0][2] += a0 * b2; acc[0][3] += a0 * b3;
      acc[1][0] += a1 * b0; acc[1][1] += a1 * b1; acc[1][2] += a1 * b2; acc[1][3] += a1 * b3;
      acc[2][0] += a2 * b0; acc[2][1] += a2 * b1; acc[2][2] += a2 * b2; acc[2][3] += a2 * b3;
      acc[3][0] += a3 * b0; acc[3][1] += a3 * b1; acc[3][2] += a3 * b2; acc[3][3] += a3 * b3;
    }
    __syncthreads();
  }

#pragma unroll
  for (int i = 0; i < 4; ++i) {
    int row = m0 + ty * 4 + i;
    float* op = xg + (size_t)row * XGLD + n0 + tx * 4;
#pragma unroll
    for (int jj = 0; jj < 4; ++jj)
      op[jj] = acc[i][jj] + bias[g0 + tx * 4 + jj];
  }
}

// ---------- sentinel fill for h_all (replay-safe, runs every launch) ----------
__global__ __launch_bounds__(256) void fill_sentinel(float* p, int n4) {
  int i = blockIdx.x * 256 + threadIdx.x;
  if (i < n4) {
    f32x4 v = {SENT, SENT, SENT, SENT};
    llc_store_f32x4(p + (size_t)i * 4, v);
  }
}

// ---------- stage B: LSTM, 64 blocks, per-wave point-to-point dataflow sync ----------
// Block = (d, slice sl of 16 units = 64 gate rows, batch-half bh of 16 batches).
// 512 threads: tid = kp*64 + cg*16 + rg. Wave kp owns k-chunk [32kp,32kp+32) and
// spins ONLY on its own chunk of h (produced by slices 2kp, 2kp+1) -- point-to-point
// dataflow instead of 16-wide all-to-all. Whh lives in per-thread registers
// (32 x f32x4, static indices). part_lds double-buffered by parity: ONE barrier/step.
__global__ __launch_bounds__(512, 2) void lstm_kernel(
    const float* __restrict__ xg,     // [NTOK][2048]
    const float* __restrict__ whh_f,  // [1024][256]
    const float* __restrict__ whh_b,  // [1024][256]
    float*       h_all)               // [4 grp][512 t][256 j][16 bl]
{
  const int bid = blockIdx.x;        // 0..63
  const int d   = bid >> 5;
  const int sl  = (bid >> 1) & 15;
  const int bh  = bid & 1;
  const int tid = threadIdx.x;
  const int kp  = tid >> 6;          // 0..7 (wave id / k-chunk)
  const int cg  = (tid >> 4) & 3;    // batch quad
  const int rg  = tid & 15;          // row quad
  const float* __restrict__ whh = d ? whh_b : whh_f;

  __shared__ float h_lds[256 * 20];          // h_t[k][bl+pad]              (20 KB)
  __shared__ float part_lds[2][8 * 16 * 68]; // parity part[kp][bl][row+pad](69.6 KB)

  // ---- per-thread weight registers: rows rg*4..+4 of the slice, k-chunk kp ----
  // (one-time global load; static-indexed f32x4 array stays in VGPRs)
  f32x4 wreg[4][8];
#pragma unroll
  for (int r = 0; r < 4; ++r) {
    const int row_l = rg * 4 + r;                            // 0..63 = gt*16+u
    const int grow  = (row_l >> 4) * 256 + sl * 16 + (row_l & 15);
    const float* rp = whh + (size_t)grow * H_ + kp * 32;
#pragma unroll
    for (int q = 0; q < 8; ++q) wreg[r][q] = *(const f32x4*)(rp + q * 4);
  }

  for (int idx = tid; idx < 256 * 20; idx += 512) h_lds[idx] = 0.f;
  __syncthreads();

  float c = 0.f;
  float* hgrp = h_all + (size_t)(d * 2 + bh) * (L_ * 4096);  // [512][256][16]

  const int u_r  = tid >> 4;   // reduce-phase unit (tid<256)
  const int bl_r = tid & 15;   // reduce-phase batch-in-half

  // xg prefetch registers (tid<256)
  const float* xbase = xg + ((size_t)(bh * 16 + bl_r) * L_) * XGLD + d * 1024 + sl * 16 + u_r;
  float x0 = 0.f, x1 = 0.f, x2 = 0.f, x3 = 0.f;
  if (tid < 256) {
    const int t0 = d ? (L_ - 1) : 0;
    const float* xp = xbase + (size_t)t0 * XGLD;
    x0 = xp[0]; x1 = xp[256]; x2 = xp[512]; x3 = xp[768];
  }

  // spin mapping: lane covers j0 and j0+16 of own chunk, batch quad bq
  const int lane = tid & 63;
  const int j0   = kp * 32 + (lane >> 2);
  const int bq   = lane & 3;

  for (int s = 0; s < L_; ++s) {
    const int t = d ? (L_ - 1 - s) : s;

    // ---- per-wave spin on OWN k-chunk of h(prev step) ----
    if (s > 0) {
      const int tp = d ? (t + 1) : (t - 1);
      const float* hsrc = hgrp + (size_t)tp * 4096;          // [256 j][16 bl]
      const float* p0 = hsrc + j0 * 16 + bq * 4;
      const float* p1 = p0 + 16 * 16;
      f32x4 v0, v1;
      bool bad;
      do {
        v0 = llc_load_f32x4(p0);
        v1 = llc_load_f32x4(p1);
        asm volatile("s_waitcnt vmcnt(0)" ::: "memory");
        __builtin_amdgcn_sched_barrier(0);
        bad = (v0.x == SENT) | (v0.y == SENT) | (v0.z == SENT) | (v0.w == SENT) |
              (v1.x == SENT) | (v1.y == SENT) | (v1.z == SENT) | (v1.w == SENT);
      } while (bad);
      *(f32x4*)&h_lds[j0 * 20 + bq * 4] = v0;
      *(f32x4*)&h_lds[(j0 + 16) * 20 + bq * 4] = v1;
    }

    // ---- 4x4 register-tiled partial GEMM over own 32-deep k-chunk ----
    {
      float acc[4][4] = {};
      const int kb = kp * 32;
#pragma unroll
      for (int i = 0; i < 32; ++i) {
        f32x4 hv = *(const f32x4*)&h_lds[(kb + i) * 20 + cg * 4];
        const int q = i >> 2, e = i & 3;
        const float w0 = wreg[0][q][e], w1 = wreg[1][q][e];
        const float w2 = wreg[2][q][e], w3 = wreg[3][q][e];
        acc[0][0] += w0 * hv.x; acc[0][1] += w0 * hv.y;
        acc[0][2] += w0 * hv.z; acc[0][3] += w0 * hv.w;
        acc[1][0] += w1 * hv.x; acc[1][1] += w1 * hv.y;
        acc[1][2] += w1 * hv.z; acc[1][3] += w1 * hv.w;
        acc[2][0] += w2 * hv.x; acc[2][1] += w2 * hv.y;
        acc[2][2] += w2 * hv.z; acc[2][3] += w2 * hv.w;
        acc[3][0] += w3 * hv.x; acc[3][1] += w3 * hv.y;
        acc[3][2] += w3 * hv.z; acc[3][3] += w3 * hv.w;
      }
#pragma unroll
      for (int cc = 0; cc < 4; ++cc) {
        f32x4 pv = {acc[0][cc], acc[1][cc], acc[2][cc], acc[3][cc]};
        *(f32x4*)&part_lds[s & 1][kp * 1088 + (cg * 4 + cc) * 68 + rg * 4] = pv;
      }
    }
    __syncthreads();   // the ONE barrier per step: all partials in parity buffer

    // ---- reduce over kp, activate, update state, publish h to LLC ----
    if (tid < 256) {
      float g0 = x0, g1 = x1, g2 = x2, g3 = x3;
#pragma unroll
      for (int k2 = 0; k2 < 8; ++k2) {
        const float* pp = &part_lds[s & 1][k2 * 1088 + bl_r * 68 + u_r];
        g0 += pp[0]; g1 += pp[16]; g2 += pp[32]; g3 += pp[48];
      }
      float gi = sigmoidf_(g0);
      float gf = sigmoidf_(g1);
      float gg = tanhf(g2);
      float go = sigmoidf_(g3);
      c = gf * c + gi * gg;
      float h = go * tanhf(c);
      llc_store_f32(&hgrp[((size_t)t * 256 + sl * 16 + u_r) * 16 + bl_r], h);
      if (s < L_ - 1) {                       // prefetch next xg
        const int tn = d ? (t - 1) : (t + 1);
        const float* xp = xbase + (size_t)tn * XGLD;
        x0 = xp[0]; x1 = xp[256]; x2 = xp[512]; x3 = xp[768];
      }
    }
    // no second barrier: next GEMM writes the other parity buffer; waves 4..7
    // proceed straight to their spin while waves 0..3 reduce/publish.
  }
}

// ---------- emissions: per (t, bh) tile, em[b][t][tag] = bout + h_f.Wf + h_b.Wb ------
__global__ __launch_bounds__(256) void emis_kernel(
    const float* __restrict__ h_all,  // [4][512][256][16]
    const float* __restrict__ wout,   // [4][512]
    const float* __restrict__ bout,   // [4]
    float* __restrict__ em)           // [32][512][4]
{
  __shared__ float hf_l[4096];   // [j][bl]
  __shared__ float hb_l[4096];
  __shared__ float wsl[2048];
  __shared__ float red[256];

  const int t  = blockIdx.x >> 1;
  const int bh = blockIdx.x & 1;
  const int tid = threadIdx.x;
  const float* hfp = h_all + ((size_t)(0 + bh) * L_ + t) * 4096;
  const float* hbp = h_all + ((size_t)(2 + bh) * L_ + t) * 4096;

  for (int i = tid; i < 1024; i += 256) {
    *(f32x4*)&hf_l[i * 4] = *(const f32x4*)&hfp[i * 4];
    *(f32x4*)&hb_l[i * 4] = *(const f32x4*)&hbp[i * 4];
  }
  for (int i = tid; i < 2048; i += 256) wsl[i] = wout[i];
  __syncthreads();

  const int bl = tid & 15, tag = (tid >> 4) & 3, ch = tid >> 6;
  float s = 0.f;
#pragma unroll 8
  for (int jj = 0; jj < 64; ++jj) {
    const int j = ch * 64 + jj;
    s += hf_l[j * 16 + bl] * wsl[tag * 512 + j]
       + hb_l[j * 16 + bl] * wsl[tag * 512 + 256 + j];
  }
  red[tid] = s;
  __syncthreads();
  if (tid < 64) {
    const int tg = tid >> 4, bb = tid & 15;
    float v = red[tid] + red[tid + 64] + red[tid + 128] + red[tid + 192];
    em[((size_t)(bh * 16 + bb) * L_ + t) * 4 + tg] = v + bout[tg];
  }
}

// ---------- Viterbi decode: one block per batch, em/hist staged in LDS ----------
__global__ __launch_bounds__(64) void viterbi_kernel(
    const float* __restrict__ em,      // [32][512][4]  (bias included)
    const float* __restrict__ trans,   // [4][4]
    const float* __restrict__ strans,  // [4]
    const float* __restrict__ etrans,  // [4]
    const int*   __restrict__ mask,    // [32][512]
    int* __restrict__ out)             // [32][512]
{
  __shared__ float em_l[512 * 4];
  __shared__ int   msk_l[512];
  __shared__ int   hist_l[512 * 4];
  __shared__ int   tags_l[512];

  const int b = blockIdx.x;
  const int tid = threadIdx.x;
  const float* ep = em + (size_t)b * L_ * 4;

  for (int i = tid; i < 512; i += 64) {
    *(f32x4*)&em_l[i * 4] = *(const f32x4*)&ep[i * 4];
    msk_l[i] = mask[b * L_ + i];
  }
  __syncthreads();

  if (tid == 0) {
    float tr[4][4];
#pragma unroll
    for (int i = 0; i < 4; ++i)
#pragma unroll
      for (int jj = 0; jj < 4; ++jj) tr[i][jj] = trans[i * 4 + jj];

    float sc[4];
#pragma unroll
    for (int tag = 0; tag < 4; ++tag) sc[tag] = strans[tag] + em_l[tag];

    for (int t = 1; t < L_; ++t) {
      float ns[4];
#pragma unroll
      for (int to = 0; to < 4; ++to) {
        float best = sc[0] + tr[0][to];
        int bf = 0;
#pragma unroll
        for (int fr = 1; fr < 4; ++fr) {
          float v = sc[fr] + tr[fr][to];
          if (v > best) { best = v; bf = fr; }
        }
        ns[to] = best + em_l[t * 4 + to];
        hist_l[t * 4 + to] = bf;
      }
      const int mt = msk_l[t];
#pragma unroll
      for (int to = 0; to < 4; ++to) sc[to] = mt ? ns[to] : sc[to];
    }

#pragma unroll
    for (int tag = 0; tag < 4; ++tag) sc[tag] += etrans[tag];
    int cur = 0;
    float best = sc[0];
#pragma unroll
    for (int i = 1; i < 4; ++i)
      if (sc[i] > best) { best = sc[i]; cur = i; }

    tags_l[L_ - 1] = msk_l[L_ - 1] ? cur : 0;
    for (int t = L_ - 1; t >= 1; --t) {
      if (msk_l[t]) cur = hist_l[t * 4 + cur];
      tags_l[t - 1] = msk_l[t - 1] ? cur : 0;
    }
  }
  __syncthreads();
  for (int i = tid; i < 512; i += 64) out[b * L_ + i] = tags_l[i];
}

extern "C" void kernel_launch(void* const* d_in, const int* in_sizes, int n_in,
                              void* d_out, int out_size, void* d_ws, size_t ws_size,
                              hipStream_t stream) {
  const int*   word_ids = (const int*)d_in[0];
  const int*   mask     = (const int*)d_in[1];
  // d_in[2] label_ids: unused
  const float* emb   = (const float*)d_in[3];
  const float* Wih_f = (const float*)d_in[4];
  const float* Whh_f = (const float*)d_in[5];
  const float* b_f   = (const float*)d_in[6];
  const float* Wih_b = (const float*)d_in[7];
  const float* Whh_b = (const float*)d_in[8];
  const float* b_b   = (const float*)d_in[9];
  const float* W_out = (const float*)d_in[10];
  const float* b_out = (const float*)d_in[11];
  const float* trans = (const float*)d_in[12];
  const float* strans = (const float*)d_in[13];
  const float* etrans = (const float*)d_in[14];
  int* out = (int*)d_out;

  float* xg    = (float*)d_ws;                             // 128 MiB
  float* h_all = xg + (size_t)NTOK * XGLD;                 // 4*512*4096 f32 = 32 MiB
  float* em    = h_all + (size_t)4 * L_ * 4096;            // 256 KiB

  const int n4 = 4 * L_ * 4096 / 4;                        // 2,097,152 f32x4
  fill_sentinel<<<(n4 + 255) / 256, 256, 0, stream>>>(h_all, n4);
  xproj_kernel<<<dim3(32, 256), 256, 0, stream>>>(word_ids, emb, Wih_f, Wih_b, b_f, b_b, xg);
  lstm_kernel<<<64, 512, 0, stream>>>(xg, Whh_f, Whh_b, h_all);
  emis_kernel<<<1024, 256, 0, stream>>>(h_all, W_out, b_out, em);
  viterbi_kernel<<<32, 64, 0, stream>>>(em, trans, strans, etrans, mask, out);
}

// Round 10
// 1507.494 us; speedup vs baseline: 2.5472x; 1.3235x over previous
//
#include <hip/hip_runtime.h>
#include <math.h>

#define B_   32
#define L_   512
#define E_   300
#define H_   256
#define T_   4
#define NTOK 16384  // B*L
#define XGLD 2048   // 2 directions * 4H
#define SENT 2.0f   // impossible h value: |h| = |sigm*tanh| < 1

typedef float f32x4 __attribute__((ext_vector_type(4)));
typedef float f32x2 __attribute__((ext_vector_type(2)));

__device__ __forceinline__ float fsigmoid_(float x) { return 1.0f / (1.0f + __expf(-x)); }
__device__ __forceinline__ float ftanh_(float x) {
  return 1.0f - 2.0f / (__expf(2.0f * x) + 1.0f);   // exact limits at +-inf
}

// LLC-coherent (agent-scope) vector ops: sc0 sc1 bypass L1/L2 like relaxed
// agent atomics, but vectorized. Caller must s_waitcnt vmcnt before using loads.
__device__ __forceinline__ void llc_store_f32(float* p, float v) {
  asm volatile("global_store_dword %0, %1, off sc0 sc1" :: "v"(p), "v"(v) : "memory");
}
__device__ __forceinline__ void llc_store_f32x4(float* p, f32x4 v) {
  asm volatile("global_store_dwordx4 %0, %1, off sc0 sc1" :: "v"(p), "v"(v) : "memory");
}
__device__ __forceinline__ f32x4 llc_load_f32x4(const float* p) {
  f32x4 r;
  asm volatile("global_load_dwordx4 %0, %1, off sc0 sc1" : "=&v"(r) : "v"(p) : "memory");
  return r;
}

// ---------- stage A: xg[row][d*1024+g] = emb[wid[row]] . Wih_d[g] + b_d[g] ----------
#define BM 64
#define BN 64
#define BK 20
__global__ __launch_bounds__(256) void xproj_kernel(
    const int*   __restrict__ wid,    // [NTOK]
    const float* __restrict__ emb,    // [V][300]
    const float* __restrict__ wih_f,  // [1024][300]
    const float* __restrict__ wih_b,
    const float* __restrict__ b_f,
    const float* __restrict__ b_b,
    float* __restrict__ xg)           // [NTOK][2048]
{
  __shared__ float As[BM][BK + 1];
  __shared__ float Bs[BK][BN];
  __shared__ int   wid_s[BM];

  int tid = threadIdx.x;
  int m0 = blockIdx.y * BM;
  int n0 = blockIdx.x * BN;            // global col 0..2047
  int d  = n0 >> 10;
  const float* wih  = d ? wih_b : wih_f;
  const float* bias = d ? b_b  : b_f;
  int g0 = n0 & 1023;

  if (tid < BM) wid_s[tid] = wid[m0 + tid];
  __syncthreads();

  int lm = tid >> 2;          // 0..63
  int lk = (tid & 3) * 5;     // 0,5,10,15
  int tx = tid & 15, ty = tid >> 4;

  float acc[4][4] = {};

  for (int k0 = 0; k0 < 300; k0 += BK) {
    const float* erow = emb + (size_t)wid_s[lm] * E_ + k0 + lk;
#pragma unroll
    for (int i = 0; i < 5; ++i) As[lm][lk + i] = erow[i];
    const float* wrow = wih + (size_t)(g0 + lm) * E_ + k0 + lk;
#pragma unroll
    for (int i = 0; i < 5; ++i) Bs[lk + i][lm] = wrow[i];
    __syncthreads();
#pragma unroll
    for (int k = 0; k < BK; ++k) {
      float a0 = As[ty * 4 + 0][k], a1 = As[ty * 4 + 1][k];
      float a2 = As[ty * 4 + 2][k], a3 = As[ty * 4 + 3][k];
      float b0 = Bs[k][tx * 4 + 0], b1 = Bs[k][tx * 4 + 1];
      float b2 = Bs[k][tx * 4 + 2], b3 = Bs[k][tx * 4 + 3];
      acc[0][0] += a0 * b0; acc[0][1] += a0 * b1; acc[0][2] += a0 * b2; acc[0][3] += a0 * b3;
      acc[1][0] += a1 * b0; acc[1][1] += a1 * b1; acc[1][2] += a1 * b2; acc[1][3] += a1 * b3;
      acc[2][0] += a2 * b0; acc[2][1] += a2 * b1; acc[2][2] += a2 * b2; acc[2][3] += a2 * b3;
      acc[3][0] += a3 * b0; acc[3][1] += a3 * b1; acc[3][2] += a3 * b2; acc[3][3] += a3 * b3;
    }
    __syncthreads();
  }

#pragma unroll
  for (int i = 0; i < 4; ++i) {
    int row = m0 + ty * 4 + i;
    float* op = xg + (size_t)row * XGLD + n0 + tx * 4;
#pragma unroll
    for (int jj = 0; jj < 4; ++jj)
      op[jj] = acc[i][jj] + bias[g0 + tx * 4 + jj];
  }
}

// ---------- sentinel fill for h_all (replay-safe, runs every launch) ----------
__global__ __launch_bounds__(256) void fill_sentinel(float* p, int n4) {
  int i = blockIdx.x * 256 + threadIdx.x;
  if (i < n4) {
    f32x4 v = {SENT, SENT, SENT, SENT};
    llc_store_f32x4(p + (size_t)i * 4, v);
  }
}

// ---------- stage B: LSTM, 128 blocks (batch-quarters), p2p dataflow sync ----------
// Block = (d, q batch-quarter of 8, sl slice of 16 units = 64 gate rows).
// Group = (d,q): 16 slice-blocks exchange h. 512 threads: tid = kp*64 + cg*16 + rg.
// Wave kp owns k-chunk [32kp,+32), spins only on its chunk (2 producer blocks).
// Whh in per-thread registers (4 rows x 32 k, static). Tile 4 rows x 2 batches.
// part_lds parity double-buffer: ONE barrier per step.
__global__ __launch_bounds__(512, 2) void lstm_kernel(
    const float* __restrict__ xg,     // [NTOK][2048]
    const float* __restrict__ whh_f,  // [1024][256]
    const float* __restrict__ whh_b,  // [1024][256]
    float*       h_all)               // [8 grp][512 t][256 j][8 bl]
{
  const int bid = blockIdx.x;        // 0..127
  const int d   = bid >> 6;
  const int q   = (bid >> 4) & 3;    // batch quarter
  const int sl  = bid & 15;          // slice
  const int tid = threadIdx.x;
  const int kp  = tid >> 6;          // 0..7 (wave id / k-chunk)
  const int cg  = (tid >> 4) & 3;    // batch PAIR index (2 batches each)
  const int rg  = tid & 15;          // row quad
  const float* __restrict__ whh = d ? whh_b : whh_f;

  __shared__ float h_lds[256 * 12];          // h_t[k][bl(8)+pad]            (12 KB)
  __shared__ float part_lds[2][8 * 8 * 68];  // parity part[kp][bl][row+pad] (34.8 KB)

  // ---- per-thread weight registers: rows rg*4..+4, k-chunk kp (static f32x4) ----
  f32x4 wreg[4][8];
#pragma unroll
  for (int r = 0; r < 4; ++r) {
    const int row_l = rg * 4 + r;                            // 0..63 = gt*16+u
    const int grow  = (row_l >> 4) * 256 + sl * 16 + (row_l & 15);
    const float* rp = whh + (size_t)grow * H_ + kp * 32;
#pragma unroll
    for (int qq = 0; qq < 8; ++qq) wreg[r][qq] = *(const f32x4*)(rp + qq * 4);
  }

  for (int idx = tid; idx < 256 * 12; idx += 512) h_lds[idx] = 0.f;
  __syncthreads();

  float c = 0.f;
  float* hgrp = h_all + (size_t)(d * 4 + q) * (L_ * 2048);   // [512 t][256 j][8 bl]

  const int u_r  = tid >> 3;   // reduce-phase unit (tid<128)
  const int bl_r = tid & 7;    // reduce-phase batch-in-quarter

  // xg prefetch registers (tid<128)
  const float* xbase = xg + ((size_t)(q * 8 + bl_r) * L_) * XGLD + d * 1024 + sl * 16 + u_r;
  float x0 = 0.f, x1 = 0.f, x2 = 0.f, x3 = 0.f;
  if (tid < 128) {
    const int t0 = d ? (L_ - 1) : 0;
    const float* xp = xbase + (size_t)t0 * XGLD;
    x0 = xp[0]; x1 = xp[256]; x2 = xp[512]; x3 = xp[768];
  }

  // spin mapping: lane covers j0 of own chunk, batch-quad bq (8 bl = 2 quads)
  const int lane = tid & 63;
  const int j0   = kp * 32 + (lane >> 1);
  const int bq   = lane & 1;

  for (int s = 0; s < L_; ++s) {
    const int t = d ? (L_ - 1 - s) : s;

    // ---- per-wave spin on OWN k-chunk of h(prev step) ----
    if (s > 0) {
      const int tp = d ? (t + 1) : (t - 1);
      const float* p0 = hgrp + (size_t)tp * 2048 + j0 * 8 + bq * 4;
      f32x4 v0;
      bool bad;
      do {
        v0 = llc_load_f32x4(p0);
        asm volatile("s_waitcnt vmcnt(0)" ::: "memory");
        __builtin_amdgcn_sched_barrier(0);
        bad = (v0.x == SENT) | (v0.y == SENT) | (v0.z == SENT) | (v0.w == SENT);
      } while (bad);
      *(f32x4*)&h_lds[j0 * 12 + bq * 4] = v0;
    }

    // ---- 4 rows x 2 batches register-tiled partial GEMM over own k-chunk ----
    {
      float acc[4][2] = {};
      const int kb = kp * 32;
#pragma unroll
      for (int i = 0; i < 32; ++i) {
        f32x2 hv = *(const f32x2*)&h_lds[(kb + i) * 12 + cg * 2];
        const int qq = i >> 2, e = i & 3;
        const float w0 = wreg[0][qq][e], w1 = wreg[1][qq][e];
        const float w2 = wreg[2][qq][e], w3 = wreg[3][qq][e];
        acc[0][0] += w0 * hv.x; acc[0][1] += w0 * hv.y;
        acc[1][0] += w1 * hv.x; acc[1][1] += w1 * hv.y;
        acc[2][0] += w2 * hv.x; acc[2][1] += w2 * hv.y;
        acc[3][0] += w3 * hv.x; acc[3][1] += w3 * hv.y;
      }
#pragma unroll
      for (int cc = 0; cc < 2; ++cc) {
        f32x4 pv = {acc[0][cc], acc[1][cc], acc[2][cc], acc[3][cc]};
        *(f32x4*)&part_lds[s & 1][kp * 544 + (cg * 2 + cc) * 68 + rg * 4] = pv;
      }
    }
    __syncthreads();   // the ONE barrier per step

    // ---- reduce over kp, activate, update state, publish h to LLC ----
    if (tid < 128) {
      float g0 = x0, g1 = x1, g2 = x2, g3 = x3;
#pragma unroll
      for (int k2 = 0; k2 < 8; ++k2) {
        const float* pp = &part_lds[s & 1][k2 * 544 + bl_r * 68 + u_r];
        g0 += pp[0]; g1 += pp[16]; g2 += pp[32]; g3 += pp[48];
      }
      float gi = fsigmoid_(g0);
      float gf = fsigmoid_(g1);
      float gg = ftanh_(g2);
      float go = fsigmoid_(g3);
      c = gf * c + gi * gg;
      float h = go * ftanh_(c);
      llc_store_f32(&hgrp[(size_t)t * 2048 + (sl * 16 + u_r) * 8 + bl_r], h);
      if (s < L_ - 1) {                       // prefetch next xg
        const int tn = d ? (t - 1) : (t + 1);
        const float* xp = xbase + (size_t)tn * XGLD;
        x0 = xp[0]; x1 = xp[256]; x2 = xp[512]; x3 = xp[768];
      }
    }
    // no second barrier: next GEMM writes the other parity buffer; spin regions
    // of h_lds are wave-private.
  }
}

// ---------- emissions: block = (t, q); em[b][t][tag] = bout + h_f.Wf + h_b.Wb ------
__global__ __launch_bounds__(256) void emis_kernel(
    const float* __restrict__ h_all,  // [8][512][256][8]
    const float* __restrict__ wout,   // [4][512]
    const float* __restrict__ bout,   // [4]
    float* __restrict__ em)           // [32][512][4]
{
  __shared__ float hf_l[2048];   // [j][bl(8)]
  __shared__ float hb_l[2048];
  __shared__ float wsl[2048];
  __shared__ float red[256];

  const int t  = blockIdx.x >> 2;
  const int q  = blockIdx.x & 3;
  const int tid = threadIdx.x;
  const float* hfp = h_all + ((size_t)(0 + q) * L_ + t) * 2048;
  const float* hbp = h_all + ((size_t)(4 + q) * L_ + t) * 2048;

  for (int i = tid; i < 512; i += 256) {
    *(f32x4*)&hf_l[i * 4] = *(const f32x4*)&hfp[i * 4];
    *(f32x4*)&hb_l[i * 4] = *(const f32x4*)&hbp[i * 4];
  }
  for (int i = tid; i < 2048; i += 256) wsl[i] = wout[i];
  __syncthreads();

  const int bl = tid & 7, tag = (tid >> 3) & 3, ch = tid >> 5;   // ch 0..7
  float s = 0.f;
#pragma unroll 8
  for (int jj = 0; jj < 32; ++jj) {
    const int j = ch * 32 + jj;
    s += hf_l[j * 8 + bl] * wsl[tag * 512 + j]
       + hb_l[j * 8 + bl] * wsl[tag * 512 + 256 + j];
  }
  red[tid] = s;
  __syncthreads();
  if (tid < 32) {
    float v = bout[tid >> 3];
#pragma unroll
    for (int chh = 0; chh < 8; ++chh) v += red[chh * 32 + tid];
    em[((size_t)(q * 8 + bl) * L_ + t) * 4 + (tid >> 3)] = v;
  }
}

// ---------- Viterbi decode: one block per batch, em/hist staged in LDS ----------
__global__ __launch_bounds__(64) void viterbi_kernel(
    const float* __restrict__ em,      // [32][512][4]  (bias included)
    const float* __restrict__ trans,   // [4][4]
    const float* __restrict__ strans,  // [4]
    const float* __restrict__ etrans,  // [4]
    const int*   __restrict__ mask,    // [32][512]
    int* __restrict__ out)             // [32][512]
{
  __shared__ float em_l[512 * 4];
  __shared__ int   msk_l[512];
  __shared__ int   hist_l[512 * 4];
  __shared__ int   tags_l[512];

  const int b = blockIdx.x;
  const int tid = threadIdx.x;
  const float* ep = em + (size_t)b * L_ * 4;

  for (int i = tid; i < 512; i += 64) {
    *(f32x4*)&em_l[i * 4] = *(const f32x4*)&ep[i * 4];
    msk_l[i] = mask[b * L_ + i];
  }
  __syncthreads();

  if (tid == 0) {
    float tr[4][4];
#pragma unroll
    for (int i = 0; i < 4; ++i)
#pragma unroll
      for (int jj = 0; jj < 4; ++jj) tr[i][jj] = trans[i * 4 + jj];

    float sc[4];
#pragma unroll
    for (int tag = 0; tag < 4; ++tag) sc[tag] = strans[tag] + em_l[tag];

    for (int t = 1; t < L_; ++t) {
      float ns[4];
#pragma unroll
      for (int to = 0; to < 4; ++to) {
        float best = sc[0] + tr[0][to];
        int bf = 0;
#pragma unroll
        for (int fr = 1; fr < 4; ++fr) {
          float v = sc[fr] + tr[fr][to];
          if (v > best) { best = v; bf = fr; }
        }
        ns[to] = best + em_l[t * 4 + to];
        hist_l[t * 4 + to] = bf;
      }
      const int mt = msk_l[t];
#pragma unroll
      for (int to = 0; to < 4; ++to) sc[to] = mt ? ns[to] : sc[to];
    }

#pragma unroll
    for (int tag = 0; tag < 4; ++tag) sc[tag] += etrans[tag];
    int cur = 0;
    float best = sc[0];
#pragma unroll
    for (int i = 1; i < 4; ++i)
      if (sc[i] > best) { best = sc[i]; cur = i; }

    tags_l[L_ - 1] = msk_l[L_ - 1] ? cur : 0;
    for (int t = L_ - 1; t >= 1; --t) {
      if (msk_l[t]) cur = hist_l[t * 4 + cur];
      tags_l[t - 1] = msk_l[t - 1] ? cur : 0;
    }
  }
  __syncthreads();
  for (int i = tid; i < 512; i += 64) out[b * L_ + i] = tags_l[i];
}

extern "C" void kernel_launch(void* const* d_in, const int* in_sizes, int n_in,
                              void* d_out, int out_size, void* d_ws, size_t ws_size,
                              hipStream_t stream) {
  const int*   word_ids = (const int*)d_in[0];
  const int*   mask     = (const int*)d_in[1];
  // d_in[2] label_ids: unused
  const float* emb   = (const float*)d_in[3];
  const float* Wih_f = (const float*)d_in[4];
  const float* Whh_f = (const float*)d_in[5];
  const float* b_f   = (const float*)d_in[6];
  const float* Wih_b = (const float*)d_in[7];
  const float* Whh_b = (const float*)d_in[8];
  const float* b_b   = (const float*)d_in[9];
  const float* W_out = (const float*)d_in[10];
  const float* b_out = (const float*)d_in[11];
  const float* trans = (const float*)d_in[12];
  const float* strans = (const float*)d_in[13];
  const float* etrans = (const float*)d_in[14];
  int* out = (int*)d_out;

  float* xg    = (float*)d_ws;                             // 128 MiB
  float* h_all = xg + (size_t)NTOK * XGLD;                 // 8*512*2048 f32 = 32 MiB
  float* em    = h_all + (size_t)8 * L_ * 2048;            // 256 KiB

  const int n4 = 8 * L_ * 2048 / 4;                        // 2,097,152 f32x4
  fill_sentinel<<<(n4 + 255) / 256, 256, 0, stream>>>(h_all, n4);
  xproj_kernel<<<dim3(32, 256), 256, 0, stream>>>(word_ids, emb, Wih_f, Wih_b, b_f, b_b, xg);
  lstm_kernel<<<128, 512, 0, stream>>>(xg, Whh_f, Whh_b, h_all);
  emis_kernel<<<2048, 256, 0, stream>>>(h_all, W_out, b_out, em);
  viterbi_kernel<<<32, 64, 0, stream>>>(em, trans, strans, etrans, mask, out);
}

// Round 11
// 1339.412 us; speedup vs baseline: 2.8668x; 1.1255x over previous
//
#include <hip/hip_runtime.h>
#include <math.h>

#define B_   32
#define L_   512
#define E_   300
#define H_   256
#define T_   4
#define NTOK 16384  // B*L
#define XGLD 2048   // 2 directions * 4H
#define SENT 2.0f   // impossible h value: |h| = |sigm*tanh| < 1

typedef float f32x4 __attribute__((ext_vector_type(4)));

__device__ __forceinline__ float fsigmoid_(float x) { return 1.0f / (1.0f + __expf(-x)); }
__device__ __forceinline__ float ftanh_(float x) {
  return 1.0f - 2.0f / (__expf(2.0f * x) + 1.0f);   // exact limits at +-inf
}

// LLC-coherent (agent-scope) vector ops: sc0 sc1 bypass L1/L2 like relaxed
// agent atomics, but vectorized. Caller must s_waitcnt vmcnt before using loads.
__device__ __forceinline__ void llc_store_f32(float* p, float v) {
  asm volatile("global_store_dword %0, %1, off sc0 sc1" :: "v"(p), "v"(v) : "memory");
}
__device__ __forceinline__ void llc_store_f32x4(float* p, f32x4 v) {
  asm volatile("global_store_dwordx4 %0, %1, off sc0 sc1" :: "v"(p), "v"(v) : "memory");
}
__device__ __forceinline__ f32x4 llc_load_f32x4(const float* p) {
  f32x4 r;
  asm volatile("global_load_dwordx4 %0, %1, off sc0 sc1" : "=&v"(r) : "v"(p) : "memory");
  return r;
}

// ---------- stage A: xg[row][d*1024+g] = emb[wid[row]] . Wih_d[g] + b_d[g] ----------
// Both A and B staged TRANSPOSED ([k][m] / [k][n]) via f32x4 so the inner loop is
// 2 ds_read_b128 per 16 FMAs. 300 = 15 tiles x BK=20; rows are 16B-aligned (300%4==0).
#define BM 64
#define BN 64
#define BK 20
__global__ __launch_bounds__(256) void xproj_kernel(
    const int*   __restrict__ wid,    // [NTOK]
    const float* __restrict__ emb,    // [V][300]
    const float* __restrict__ wih_f,  // [1024][300]
    const float* __restrict__ wih_b,
    const float* __restrict__ b_f,
    const float* __restrict__ b_b,
    float* __restrict__ xg)           // [NTOK][2048]
{
  __shared__ float Ast[BK][BM];      // [k][m]
  __shared__ float Bst[BK][BN];      // [k][n]
  __shared__ int   wid_s[BM];

  const int tid = threadIdx.x;
  const int m0 = blockIdx.y * BM;
  const int n0 = blockIdx.x * BN;    // global col 0..2047
  const int d  = n0 >> 10;
  const float* wih  = d ? wih_b : wih_f;
  const float* bias = d ? b_b  : b_f;
  const int g0 = n0 & 1023;

  if (tid < BM) wid_s[tid] = wid[m0 + tid];
  __syncthreads();

  const int row = tid & 63;          // staging row
  const int qa  = tid >> 6;          // staging quad 0..3 (5th quad by qa==0)
  const int tx = tid & 15, ty = tid >> 4;

  float acc[4][4] = {};

  for (int k0 = 0; k0 < 300; k0 += BK) {
    // ---- stage A (gathered emb rows), transposed ----
    {
      const float* erow = emb + (size_t)wid_s[row] * E_ + k0;
      f32x4 va = *(const f32x4*)(erow + qa * 4);
#pragma unroll
      for (int e = 0; e < 4; ++e) Ast[qa * 4 + e][row] = va[e];
      if (qa == 0) {
        f32x4 vb = *(const f32x4*)(erow + 16);
#pragma unroll
        for (int e = 0; e < 4; ++e) Ast[16 + e][row] = vb[e];
      }
    }
    // ---- stage B (weight rows), transposed ----
    {
      const float* wrow = wih + (size_t)(g0 + row) * E_ + k0;
      f32x4 va = *(const f32x4*)(wrow + qa * 4);
#pragma unroll
      for (int e = 0; e < 4; ++e) Bst[qa * 4 + e][row] = va[e];
      if (qa == 0) {
        f32x4 vb = *(const f32x4*)(wrow + 16);
#pragma unroll
        for (int e = 0; e < 4; ++e) Bst[16 + e][row] = vb[e];
      }
    }
    __syncthreads();

#pragma unroll
    for (int k = 0; k < BK; ++k) {
      f32x4 a4 = *(const f32x4*)&Ast[k][ty * 4];
      f32x4 b4 = *(const f32x4*)&Bst[k][tx * 4];
      acc[0][0] += a4.x * b4.x; acc[0][1] += a4.x * b4.y;
      acc[0][2] += a4.x * b4.z; acc[0][3] += a4.x * b4.w;
      acc[1][0] += a4.y * b4.x; acc[1][1] += a4.y * b4.y;
      acc[1][2] += a4.y * b4.z; acc[1][3] += a4.y * b4.w;
      acc[2][0] += a4.z * b4.x; acc[2][1] += a4.z * b4.y;
      acc[2][2] += a4.z * b4.z; acc[2][3] += a4.z * b4.w;
      acc[3][0] += a4.w * b4.x; acc[3][1] += a4.w * b4.y;
      acc[3][2] += a4.w * b4.z; acc[3][3] += a4.w * b4.w;
    }
    __syncthreads();
  }

#pragma unroll
  for (int i = 0; i < 4; ++i) {
    const int r = m0 + ty * 4 + i;
    float* op = xg + (size_t)r * XGLD + n0 + tx * 4;
#pragma unroll
    for (int jj = 0; jj < 4; ++jj)
      op[jj] = acc[i][jj] + bias[g0 + tx * 4 + jj];
  }
}

// ---------- sentinel fill for h_all (replay-safe, runs every launch) ----------
__global__ __launch_bounds__(256) void fill_sentinel(float* p, int n4) {
  int i = blockIdx.x * 256 + threadIdx.x;
  if (i < n4) {
    f32x4 v = {SENT, SENT, SENT, SENT};
    llc_store_f32x4(p + (size_t)i * 4, v);
  }
}

// ---------- stage B: LSTM, 256 blocks (batch-eighths of 4), p2p dataflow sync -------
// Block = (d, q eighth of 4 batches, sl slice of 16 units = 64 gate rows).
// Group = (d,q): 16 slice-blocks exchange h via h_all[grp][t][bl=4][j=256].
// 512 threads: tid = kp*64 + lane; lane = cg*16 + rg. Wave kp owns k-chunk
// [32kp,+32). h_lds is [bl][k] so GEMM reads ONE ds_read_b128 per 4 k.
// Whh rows in per-thread registers/AGPRs. ONE barrier per step (parity part_lds).
__global__ __launch_bounds__(512, 2) void lstm_kernel(
    const float* __restrict__ xg,     // [NTOK][2048]
    const float* __restrict__ whh_f,  // [1024][256]
    const float* __restrict__ whh_b,  // [1024][256]
    float*       h_all)               // [16 grp][512 t][4 bl][256 j]
{
  const int bid = blockIdx.x;        // 0..255
  const int d   = bid >> 7;
  const int q   = (bid >> 4) & 7;    // batch eighth
  const int sl  = bid & 15;          // slice
  const int tid = threadIdx.x;
  const int kp  = tid >> 6;          // 0..7 (wave / k-chunk)
  const int lane = tid & 63;
  const int cg  = lane >> 4;         // batch 0..3
  const int rg  = lane & 15;         // row quad
  const float* __restrict__ whh = d ? whh_b : whh_f;

  __shared__ float h_lds[4 * 260];           // h[bl][k+pad]           (4.2 KB)
  __shared__ float part_lds[2][8 * 4 * 68];  // parity [kp][bl][row+pad] (8.7 KB)

  // ---- per-thread weight registers: rows rg*4..+4, k-chunk kp (static f32x4) ----
  f32x4 wreg[4][8];
#pragma unroll
  for (int r = 0; r < 4; ++r) {
    const int row_l = rg * 4 + r;                            // 0..63 = gt*16+u
    const int grow  = (row_l >> 4) * 256 + sl * 16 + (row_l & 15);
    const float* rp = whh + (size_t)grow * H_ + kp * 32;
#pragma unroll
    for (int qq = 0; qq < 8; ++qq) wreg[r][qq] = *(const f32x4*)(rp + qq * 4);
  }

  for (int idx = tid; idx < 4 * 260; idx += 512) h_lds[idx] = 0.f;
  __syncthreads();

  float c = 0.f;
  float* hgrp = h_all + (size_t)(d * 8 + q) * (L_ * 1024);   // [512 t][4 bl][256 j]

  const int u_r  = tid >> 2;   // reduce-phase unit (tid<64)
  const int bl_r = tid & 3;    // reduce-phase batch

  // xg prefetch registers (tid<64)
  const float* xbase = xg + ((size_t)(q * 4 + bl_r) * L_) * XGLD + d * 1024 + sl * 16 + u_r;
  float x0 = 0.f, x1 = 0.f, x2 = 0.f, x3 = 0.f;
  if (tid < 64) {
    const int t0 = d ? (L_ - 1) : 0;
    const float* xp = xbase + (size_t)t0 * XGLD;
    x0 = xp[0]; x1 = xp[256]; x2 = xp[512]; x3 = xp[768];
  }

  // spin mapping: lanes 0..31 cover (bl = lane>>3, j0 = kp*32 + (lane&7)*4)
  const int sp_bl = lane >> 3;
  const int sp_j0 = kp * 32 + (lane & 7) * 4;

  for (int s = 0; s < L_; ++s) {
    const int t = d ? (L_ - 1 - s) : s;

    // ---- per-wave spin on OWN k-chunk of h(prev step) ----
    if (s > 0) {
      const int tp = d ? (t + 1) : (t - 1);
      if (lane < 32) {
        const float* p0 = hgrp + (size_t)tp * 1024 + sp_bl * 256 + sp_j0;
        f32x4 v0;
        bool bad;
        do {
          v0 = llc_load_f32x4(p0);
          asm volatile("s_waitcnt vmcnt(0)" ::: "memory");
          __builtin_amdgcn_sched_barrier(0);
          bad = (v0.x == SENT) | (v0.y == SENT) | (v0.z == SENT) | (v0.w == SENT);
        } while (bad);
        *(f32x4*)&h_lds[sp_bl * 260 + sp_j0] = v0;
      }
    }

    // ---- 4 rows x 1 batch register-tiled GEMM over own k-chunk (b128 h reads) ----
    {
      float a0 = 0.f, a1 = 0.f, a2 = 0.f, a3 = 0.f;
#pragma unroll
      for (int i = 0; i < 8; ++i) {
        f32x4 hv = *(const f32x4*)&h_lds[cg * 260 + kp * 32 + i * 4];
        a0 += wreg[0][i].x * hv.x + wreg[0][i].y * hv.y
            + wreg[0][i].z * hv.z + wreg[0][i].w * hv.w;
        a1 += wreg[1][i].x * hv.x + wreg[1][i].y * hv.y
            + wreg[1][i].z * hv.z + wreg[1][i].w * hv.w;
        a2 += wreg[2][i].x * hv.x + wreg[2][i].y * hv.y
            + wreg[2][i].z * hv.z + wreg[2][i].w * hv.w;
        a3 += wreg[3][i].x * hv.x + wreg[3][i].y * hv.y
            + wreg[3][i].z * hv.z + wreg[3][i].w * hv.w;
      }
      f32x4 pv = {a0, a1, a2, a3};
      *(f32x4*)&part_lds[s & 1][kp * 272 + cg * 68 + rg * 4] = pv;
    }
    __syncthreads();   // the ONE barrier per step

    // ---- reduce over kp, activate, update state, publish h to LLC ----
    if (tid < 64) {
      float g0 = x0, g1 = x1, g2 = x2, g3 = x3;
#pragma unroll
      for (int k2 = 0; k2 < 8; ++k2) {
        const float* pp = &part_lds[s & 1][k2 * 272 + bl_r * 68 + u_r];
        g0 += pp[0]; g1 += pp[16]; g2 += pp[32]; g3 += pp[48];
      }
      float gi = fsigmoid_(g0);
      float gf = fsigmoid_(g1);
      float gg = ftanh_(g2);
      float go = fsigmoid_(g3);
      c = gf * c + gi * gg;
      float h = go * ftanh_(c);
      llc_store_f32(&hgrp[(size_t)t * 1024 + bl_r * 256 + sl * 16 + u_r], h);
      if (s < L_ - 1) {                       // prefetch next xg
        const int tn = d ? (t - 1) : (t + 1);
        const float* xp = xbase + (size_t)tn * XGLD;
        x0 = xp[0]; x1 = xp[256]; x2 = xp[512]; x3 = xp[768];
      }
    }
    // no second barrier: next GEMM writes the other parity buffer; h_lds spin
    // regions are wave-private (each wave reads only its own k-chunk columns).
  }
}

// ---------- emissions: block = (t, q); em[b][t][tag] = bout + h_f.Wf + h_b.Wb ------
__global__ __launch_bounds__(256) void emis_kernel(
    const float* __restrict__ h_all,  // [16][512][4][256]
    const float* __restrict__ wout,   // [4][512]
    const float* __restrict__ bout,   // [4]
    float* __restrict__ em)           // [32][512][4]
{
  __shared__ float hf_l[1024];   // [bl][j]
  __shared__ float hb_l[1024];
  __shared__ float wsl[2048];

  const int t  = blockIdx.x >> 3;
  const int q  = blockIdx.x & 7;
  const int tid = threadIdx.x;
  const float* hfp = h_all + ((size_t)(0 + q) * L_ + t) * 1024;
  const float* hbp = h_all + ((size_t)(8 + q) * L_ + t) * 1024;

  if (tid < 256) {
    *(f32x4*)&hf_l[tid * 4] = *(const f32x4*)&hfp[tid * 4];
    *(f32x4*)&hb_l[tid * 4] = *(const f32x4*)&hbp[tid * 4];
  }
  for (int i = tid; i < 2048; i += 256) wsl[i] = wout[i];
  __syncthreads();

  const int bl = tid >> 6, lane = tid & 63;
  float s0 = 0.f, s1 = 0.f, s2 = 0.f, s3 = 0.f;
#pragma unroll
  for (int i = 0; i < 4; ++i) {
    const int j = i * 64 + lane;
    const float hfv = hf_l[bl * 256 + j], hbv = hb_l[bl * 256 + j];
    s0 += hfv * wsl[0 * 512 + j] + hbv * wsl[0 * 512 + 256 + j];
    s1 += hfv * wsl[1 * 512 + j] + hbv * wsl[1 * 512 + 256 + j];
    s2 += hfv * wsl[2 * 512 + j] + hbv * wsl[2 * 512 + 256 + j];
    s3 += hfv * wsl[3 * 512 + j] + hbv * wsl[3 * 512 + 256 + j];
  }
#pragma unroll
  for (int m = 1; m < 64; m <<= 1) {
    s0 += __shfl_xor(s0, m, 64);
    s1 += __shfl_xor(s1, m, 64);
    s2 += __shfl_xor(s2, m, 64);
    s3 += __shfl_xor(s3, m, 64);
  }
  if (lane == 0) {
    float* ep = em + ((size_t)(q * 4 + bl) * L_ + t) * 4;
    ep[0] = s0 + bout[0]; ep[1] = s1 + bout[1];
    ep[2] = s2 + bout[2]; ep[3] = s3 + bout[3];
  }
}

// ---------- Viterbi decode: one block per batch, em/hist staged in LDS ----------
__global__ __launch_bounds__(64) void viterbi_kernel(
    const float* __restrict__ em,      // [32][512][4]  (bias included)
    const float* __restrict__ trans,   // [4][4]
    const float* __restrict__ strans,  // [4]
    const float* __restrict__ etrans,  // [4]
    const int*   __restrict__ mask,    // [32][512]
    int* __restrict__ out)             // [32][512]
{
  __shared__ float em_l[512 * 4];
  __shared__ int   msk_l[512];
  __shared__ int   hist_l[512 * 4];
  __shared__ int   tags_l[512];

  const int b = blockIdx.x;
  const int tid = threadIdx.x;
  const float* ep = em + (size_t)b * L_ * 4;

  for (int i = tid; i < 512; i += 64) {
    *(f32x4*)&em_l[i * 4] = *(const f32x4*)&ep[i * 4];
    msk_l[i] = mask[b * L_ + i];
  }
  __syncthreads();

  if (tid == 0) {
    float tr[4][4];
#pragma unroll
    for (int i = 0; i < 4; ++i)
#pragma unroll
      for (int jj = 0; jj < 4; ++jj) tr[i][jj] = trans[i * 4 + jj];

    float sc[4];
#pragma unroll
    for (int tag = 0; tag < 4; ++tag) sc[tag] = strans[tag] + em_l[tag];

    for (int t = 1; t < L_; ++t) {
      float ns[4];
#pragma unroll
      for (int to = 0; to < 4; ++to) {
        float best = sc[0] + tr[0][to];
        int bf = 0;
#pragma unroll
        for (int fr = 1; fr < 4; ++fr) {
          float v = sc[fr] + tr[fr][to];
          if (v > best) { best = v; bf = fr; }
        }
        ns[to] = best + em_l[t * 4 + to];
        hist_l[t * 4 + to] = bf;
      }
      const int mt = msk_l[t];
#pragma unroll
      for (int to = 0; to < 4; ++to) sc[to] = mt ? ns[to] : sc[to];
    }

#pragma unroll
    for (int tag = 0; tag < 4; ++tag) sc[tag] += etrans[tag];
    int cur = 0;
    float best = sc[0];
#pragma unroll
    for (int i = 1; i < 4; ++i)
      if (sc[i] > best) { best = sc[i]; cur = i; }

    tags_l[L_ - 1] = msk_l[L_ - 1] ? cur : 0;
    for (int t = L_ - 1; t >= 1; --t) {
      if (msk_l[t]) cur = hist_l[t * 4 + cur];
      tags_l[t - 1] = msk_l[t - 1] ? cur : 0;
    }
  }
  __syncthreads();
  for (int i = tid; i < 512; i += 64) out[b * L_ + i] = tags_l[i];
}

extern "C" void kernel_launch(void* const* d_in, const int* in_sizes, int n_in,
                              void* d_out, int out_size, void* d_ws, size_t ws_size,
                              hipStream_t stream) {
  const int*   word_ids = (const int*)d_in[0];
  const int*   mask     = (const int*)d_in[1];
  // d_in[2] label_ids: unused
  const float* emb   = (const float*)d_in[3];
  const float* Wih_f = (const float*)d_in[4];
  const float* Whh_f = (const float*)d_in[5];
  const float* b_f   = (const float*)d_in[6];
  const float* Wih_b = (const float*)d_in[7];
  const float* Whh_b = (const float*)d_in[8];
  const float* b_b   = (const float*)d_in[9];
  const float* W_out = (const float*)d_in[10];
  const float* b_out = (const float*)d_in[11];
  const float* trans = (const float*)d_in[12];
  const float* strans = (const float*)d_in[13];
  const float* etrans = (const float*)d_in[14];
  int* out = (int*)d_out;

  float* xg    = (float*)d_ws;                             // 128 MiB
  float* h_all = xg + (size_t)NTOK * XGLD;                 // 16*512*1024 f32 = 33.5 MB
  float* em    = h_all + (size_t)16 * L_ * 1024;           // 256 KiB

  const int n4 = 16 * L_ * 1024 / 4;                       // 2,097,152 f32x4
  fill_sentinel<<<(n4 + 255) / 256, 256, 0, stream>>>(h_all, n4);
  xproj_kernel<<<dim3(32, 256), 256, 0, stream>>>(word_ids, emb, Wih_f, Wih_b, b_f, b_b, xg);
  lstm_kernel<<<256, 512, 0, stream>>>(xg, Whh_f, Whh_b, h_all);
  emis_kernel<<<4096, 256, 0, stream>>>(h_all, W_out, b_out, em);
  viterbi_kernel<<<32, 64, 0, stream>>>(em, trans, strans, etrans, mask, out);
}

// Round 12
// 1114.311 us; speedup vs baseline: 3.4459x; 1.2020x over previous
//
#include <hip/hip_runtime.h>
#include <math.h>

#define B_   32
#define L_   512
#define E_   300
#define H_   256
#define T_   4
#define NTOK 16384  // B*L
#define XGLD 2048   // 2 directions * 4H
#define SENT 2.0f   // impossible h value: |h| = |sigm*tanh| < 1

typedef float f32x4 __attribute__((ext_vector_type(4)));
typedef float f32x2 __attribute__((ext_vector_type(2)));

__device__ __forceinline__ float fsigmoid_(float x) { return 1.0f / (1.0f + __expf(-x)); }
__device__ __forceinline__ float ftanh_(float x) {
  return 1.0f - 2.0f / (__expf(2.0f * x) + 1.0f);   // exact limits at +-inf
}

// LLC-coherent (agent-scope) vector ops: sc0 sc1 bypass L1/L2 like relaxed
// agent atomics, but vectorized. Caller must s_waitcnt vmcnt before using loads.
__device__ __forceinline__ void llc_store_f32(float* p, float v) {
  asm volatile("global_store_dword %0, %1, off sc0 sc1" :: "v"(p), "v"(v) : "memory");
}
__device__ __forceinline__ void llc_store_f32x4(float* p, f32x4 v) {
  asm volatile("global_store_dwordx4 %0, %1, off sc0 sc1" :: "v"(p), "v"(v) : "memory");
}
__device__ __forceinline__ f32x4 llc_load_f32x4(const float* p) {
  f32x4 r;
  asm volatile("global_load_dwordx4 %0, %1, off sc0 sc1" : "=&v"(r) : "v"(p) : "memory");
  return r;
}

// ---------- stage A: xg[row][d*1024+g] = emb[wid[row]] . Wih_d[g] + b_d[g] ----------
#define BM 64
#define BN 64
#define BK 20
__global__ __launch_bounds__(256) void xproj_kernel(
    const int*   __restrict__ wid,    // [NTOK]
    const float* __restrict__ emb,    // [V][300]
    const float* __restrict__ wih_f,  // [1024][300]
    const float* __restrict__ wih_b,
    const float* __restrict__ b_f,
    const float* __restrict__ b_b,
    float* __restrict__ xg)           // [NTOK][2048]
{
  __shared__ float Ast[BK][BM];      // [k][m]
  __shared__ float Bst[BK][BN];      // [k][n]
  __shared__ int   wid_s[BM];

  const int tid = threadIdx.x;
  const int m0 = blockIdx.y * BM;
  const int n0 = blockIdx.x * BN;    // global col 0..2047
  const int d  = n0 >> 10;
  const float* wih  = d ? wih_b : wih_f;
  const float* bias = d ? b_b  : b_f;
  const int g0 = n0 & 1023;

  if (tid < BM) wid_s[tid] = wid[m0 + tid];
  __syncthreads();

  const int row = tid & 63;          // staging row
  const int qa  = tid >> 6;          // staging quad 0..3 (5th quad by qa==0)
  const int tx = tid & 15, ty = tid >> 4;

  float acc[4][4] = {};

  for (int k0 = 0; k0 < 300; k0 += BK) {
    {
      const float* erow = emb + (size_t)wid_s[row] * E_ + k0;
      f32x4 va = *(const f32x4*)(erow + qa * 4);
#pragma unroll
      for (int e = 0; e < 4; ++e) Ast[qa * 4 + e][row] = va[e];
      if (qa == 0) {
        f32x4 vb = *(const f32x4*)(erow + 16);
#pragma unroll
        for (int e = 0; e < 4; ++e) Ast[16 + e][row] = vb[e];
      }
    }
    {
      const float* wrow = wih + (size_t)(g0 + row) * E_ + k0;
      f32x4 va = *(const f32x4*)(wrow + qa * 4);
#pragma unroll
      for (int e = 0; e < 4; ++e) Bst[qa * 4 + e][row] = va[e];
      if (qa == 0) {
        f32x4 vb = *(const f32x4*)(wrow + 16);
#pragma unroll
        for (int e = 0; e < 4; ++e) Bst[16 + e][row] = vb[e];
      }
    }
    __syncthreads();

#pragma unroll
    for (int k = 0; k < BK; ++k) {
      f32x4 a4 = *(const f32x4*)&Ast[k][ty * 4];
      f32x4 b4 = *(const f32x4*)&Bst[k][tx * 4];
      acc[0][0] += a4.x * b4.x; acc[0][1] += a4.x * b4.y;
      acc[0][2] += a4.x * b4.z; acc[0][3] += a4.x * b4.w;
      acc[1][0] += a4.y * b4.x; acc[1][1] += a4.y * b4.y;
      acc[1][2] += a4.y * b4.z; acc[1][3] += a4.y * b4.w;
      acc[2][0] += a4.z * b4.x; acc[2][1] += a4.z * b4.y;
      acc[2][2] += a4.z * b4.z; acc[2][3] += a4.z * b4.w;
      acc[3][0] += a4.w * b4.x; acc[3][1] += a4.w * b4.y;
      acc[3][2] += a4.w * b4.z; acc[3][3] += a4.w * b4.w;
    }
    __syncthreads();
  }

#pragma unroll
  for (int i = 0; i < 4; ++i) {
    const int r = m0 + ty * 4 + i;
    float* op = xg + (size_t)r * XGLD + n0 + tx * 4;
#pragma unroll
    for (int jj = 0; jj < 4; ++jj)
      op[jj] = acc[i][jj] + bias[g0 + tx * 4 + jj];
  }
}

// ---------- sentinel fill for h_all (replay-safe, runs every launch) ----------
__global__ __launch_bounds__(256) void fill_sentinel(float* p, int n4) {
  int i = blockIdx.x * 256 + threadIdx.x;
  if (i < n4) {
    f32x4 v = {SENT, SENT, SENT, SENT};
    llc_store_f32x4(p + (size_t)i * 4, v);
  }
}

// ---------- stage B: LSTM, 256 blocks, 2-phase batch pipeline hiding LLC RTT ---------
// Block = (d, q eighth of 4 batches, sl slice of 16 units = 64 gate rows, unit-major).
// Phases: A = batches {0,1}, B = {2,3}. 4-slot schedule per step:
//   slot1 GEMM_A(s) | slot2 reduce_A(s)+pub || spin_B(s-1) | slot3 GEMM_B(s) |
//   slot4 reduce_B(s)+pub || spin_A(s)
// Each spin's target was published >= 1 GEMM earlier -> LLC RTT hides under compute.
// Rows are UNIT-MAJOR (row = u*4 + gate) so the reduce reads gates as one b128.
__global__ __launch_bounds__(512, 2) void lstm_kernel(
    const float* __restrict__ xg,     // [NTOK][2048]
    const float* __restrict__ whh_f,  // [1024][256]
    const float* __restrict__ whh_b,  // [1024][256]
    float*       h_all)               // [16 grp][512 t][4 bl][256 j]
{
  const int bid = blockIdx.x;        // 0..255
  const int d   = bid >> 7;
  const int q   = (bid >> 4) & 7;    // batch eighth
  const int sl  = bid & 15;          // slice
  const int tid = threadIdx.x;
  const int kp  = tid >> 6;          // 0..7 (wave / k-chunk)
  const int lane = tid & 63;
  const int bl_loc = lane >> 5;      // batch within phase (0/1)
  const int rg  = lane & 31;         // row pair index
  const float* __restrict__ whh = d ? whh_b : whh_f;

  __shared__ float h_lds[4 * 260];           // h[bl][k+pad]             (4.2 KB)
  __shared__ float part_lds[2 * 8 * 2 * 72]; // [ph][kp][bl_loc][row+pad] (9.2 KB)

  // ---- per-thread weights: rows rg*2, rg*2+1 (unit-major), k-chunk kp ----
  f32x4 wreg[2][8];
#pragma unroll
  for (int r = 0; r < 2; ++r) {
    const int row_l = rg * 2 + r;            // u*4 + gt
    const int u  = row_l >> 2;
    const int gt = row_l & 3;
    const int grow = gt * 256 + sl * 16 + u;
    const float* rp = whh + (size_t)grow * H_ + kp * 32;
#pragma unroll
    for (int qq = 0; qq < 8; ++qq) wreg[r][qq] = *(const f32x4*)(rp + qq * 4);
  }

  for (int idx = tid; idx < 4 * 260; idx += 512) h_lds[idx] = 0.f;
  __syncthreads();

  float* hgrp = h_all + (size_t)(d * 8 + q) * (L_ * 1024);   // [512 t][4 bl][256 j]

  // reduce-thread state: tid<32 -> phase A (bl 0,1); tid 32..63 -> phase B (bl 2,3)
  const int r_u  = (tid & 31) >> 1;
  const int r_bl = (tid < 32) ? (tid & 1) : (2 + (tid & 1));
  float c = 0.f;
  const float* xbase = xg + ((size_t)(q * 4 + r_bl) * L_) * XGLD + d * 1024 + sl * 16 + r_u;
  float x0 = 0.f, x1 = 0.f, x2 = 0.f, x3 = 0.f;
  if (tid < 64) {
    const int t0 = d ? (L_ - 1) : 0;
    const float* xp = xbase + (size_t)t0 * XGLD;
    x0 = xp[0]; x1 = xp[256]; x2 = xp[512]; x3 = xp[768];
  }

#define GEMM_PHASE(PH, BLBASE)                                                \
  do {                                                                        \
    const int blg = (BLBASE) + bl_loc;                                        \
    const float* hb = &h_lds[blg * 260 + kp * 32];                            \
    float a0 = 0.f, a1 = 0.f;                                                 \
    _Pragma("unroll")                                                         \
    for (int i = 0; i < 8; ++i) {                                             \
      f32x4 hv = *(const f32x4*)(hb + i * 4);                                 \
      a0 += wreg[0][i].x * hv.x + wreg[0][i].y * hv.y                         \
          + wreg[0][i].z * hv.z + wreg[0][i].w * hv.w;                        \
      a1 += wreg[1][i].x * hv.x + wreg[1][i].y * hv.y                         \
          + wreg[1][i].z * hv.z + wreg[1][i].w * hv.w;                        \
    }                                                                         \
    f32x2 pv = {a0, a1};                                                      \
    *(f32x2*)&part_lds[(PH) * 1152 + kp * 144 + bl_loc * 72 + rg * 2] = pv;   \
  } while (0)

#define REDUCE_PUBLISH(PH, TT, TN)                                            \
  do {                                                                        \
    f32x4 g = {x0, x1, x2, x3};                                               \
    _Pragma("unroll")                                                         \
    for (int k2 = 0; k2 < 8; ++k2)                                            \
      g += *(const f32x4*)&part_lds[(PH) * 1152 + k2 * 144                    \
                                    + (tid & 1) * 72 + r_u * 4];              \
    float gi = fsigmoid_(g.x);                                                \
    float gf = fsigmoid_(g.y);                                                \
    float gg = ftanh_(g.z);                                                   \
    float go = fsigmoid_(g.w);                                                \
    c = gf * c + gi * gg;                                                     \
    float h = go * ftanh_(c);                                                 \
    llc_store_f32(&hgrp[(size_t)(TT) * 1024 + r_bl * 256 + sl * 16 + r_u], h);\
    if ((TN) >= 0) {                                                          \
      const float* xp = xbase + (size_t)(TN) * XGLD;                          \
      x0 = xp[0]; x1 = xp[256]; x2 = xp[512]; x3 = xp[768];                   \
    }                                                                         \
  } while (0)

#define SPIN_LOAD(BLBASE, TT)                                                 \
  do {                                                                        \
    const int i = tid - 64;                                                   \
    const int blg = (BLBASE) + (i >> 6);                                      \
    const int j4 = (i & 63) * 4;                                              \
    const float* p0 = hgrp + (size_t)(TT) * 1024 + blg * 256 + j4;            \
    f32x4 v0;                                                                 \
    bool bad;                                                                 \
    do {                                                                      \
      v0 = llc_load_f32x4(p0);                                                \
      asm volatile("s_waitcnt vmcnt(0)" ::: "memory");                        \
      __builtin_amdgcn_sched_barrier(0);                                      \
      bad = (v0.x == SENT) | (v0.y == SENT) | (v0.z == SENT) | (v0.w == SENT);\
    } while (bad);                                                            \
    *(f32x4*)&h_lds[blg * 260 + j4] = v0;                                     \
  } while (0)

  for (int s = 0; s < L_; ++s) {
    const int t  = d ? (L_ - 1 - s) : s;
    const int tp = d ? (t + 1) : (t - 1);          // previous step's time index
    const int tn = (s < L_ - 1) ? (d ? (t - 1) : (t + 1)) : -1;

    // ---- slot1: GEMM phase A ----
    GEMM_PHASE(0, 0);
    __syncthreads();

    // ---- slot2: reduce/publish A(s)  ||  spin B(s-1) ----
    if (tid < 32) {
      REDUCE_PUBLISH(0, t, tn);
    } else if (s > 0 && tid >= 64 && tid < 192) {
      SPIN_LOAD(2, tp);
    }
    __syncthreads();

    // ---- slot3: GEMM phase B ----
    GEMM_PHASE(1, 2);
    __syncthreads();

    // ---- slot4: reduce/publish B(s)  ||  spin A(s) ----
    if (tid >= 32 && tid < 64) {
      REDUCE_PUBLISH(1, t, tn);
    } else if (s < L_ - 1 && tid >= 64 && tid < 192) {
      SPIN_LOAD(0, t);
    }
    __syncthreads();
  }

#undef GEMM_PHASE
#undef REDUCE_PUBLISH
#undef SPIN_LOAD
}

// ---------- emissions: block = (t, q); em[b][t][tag] = bout + h_f.Wf + h_b.Wb ------
__global__ __launch_bounds__(256) void emis_kernel(
    const float* __restrict__ h_all,  // [16][512][4][256]
    const float* __restrict__ wout,   // [4][512]
    const float* __restrict__ bout,   // [4]
    float* __restrict__ em)           // [32][512][4]
{
  __shared__ float hf_l[1024];   // [bl][j]
  __shared__ float hb_l[1024];
  __shared__ float wsl[2048];

  const int t  = blockIdx.x >> 3;
  const int q  = blockIdx.x & 7;
  const int tid = threadIdx.x;
  const float* hfp = h_all + ((size_t)(0 + q) * L_ + t) * 1024;
  const float* hbp = h_all + ((size_t)(8 + q) * L_ + t) * 1024;

  if (tid < 256) {
    *(f32x4*)&hf_l[tid * 4] = *(const f32x4*)&hfp[tid * 4];
    *(f32x4*)&hb_l[tid * 4] = *(const f32x4*)&hbp[tid * 4];
  }
  for (int i = tid; i < 2048; i += 256) wsl[i] = wout[i];
  __syncthreads();

  const int bl = tid >> 6, lane = tid & 63;
  float s0 = 0.f, s1 = 0.f, s2 = 0.f, s3 = 0.f;
#pragma unroll
  for (int i = 0; i < 4; ++i) {
    const int j = i * 64 + lane;
    const float hfv = hf_l[bl * 256 + j], hbv = hb_l[bl * 256 + j];
    s0 += hfv * wsl[0 * 512 + j] + hbv * wsl[0 * 512 + 256 + j];
    s1 += hfv * wsl[1 * 512 + j] + hbv * wsl[1 * 512 + 256 + j];
    s2 += hfv * wsl[2 * 512 + j] + hbv * wsl[2 * 512 + 256 + j];
    s3 += hfv * wsl[3 * 512 + j] + hbv * wsl[3 * 512 + 256 + j];
  }
#pragma unroll
  for (int m = 1; m < 64; m <<= 1) {
    s0 += __shfl_xor(s0, m, 64);
    s1 += __shfl_xor(s1, m, 64);
    s2 += __shfl_xor(s2, m, 64);
    s3 += __shfl_xor(s3, m, 64);
  }
  if (lane == 0) {
    float* ep = em + ((size_t)(q * 4 + bl) * L_ + t) * 4;
    ep[0] = s0 + bout[0]; ep[1] = s1 + bout[1];
    ep[2] = s2 + bout[2]; ep[3] = s3 + bout[3];
  }
}

// ---------- Viterbi decode: one block per batch, em/hist staged in LDS ----------
__global__ __launch_bounds__(64) void viterbi_kernel(
    const float* __restrict__ em,      // [32][512][4]  (bias included)
    const float* __restrict__ trans,   // [4][4]
    const float* __restrict__ strans,  // [4]
    const float* __restrict__ etrans,  // [4]
    const int*   __restrict__ mask,    // [32][512]
    int* __restrict__ out)             // [32][512]
{
  __shared__ float em_l[512 * 4];
  __shared__ int   msk_l[512];
  __shared__ int   hist_l[512 * 4];
  __shared__ int   tags_l[512];

  const int b = blockIdx.x;
  const int tid = threadIdx.x;
  const float* ep = em + (size_t)b * L_ * 4;

  for (int i = tid; i < 512; i += 64) {
    *(f32x4*)&em_l[i * 4] = *(const f32x4*)&ep[i * 4];
    msk_l[i] = mask[b * L_ + i];
  }
  __syncthreads();

  if (tid == 0) {
    float tr[4][4];
#pragma unroll
    for (int i = 0; i < 4; ++i)
#pragma unroll
      for (int jj = 0; jj < 4; ++jj) tr[i][jj] = trans[i * 4 + jj];

    float sc[4];
#pragma unroll
    for (int tag = 0; tag < 4; ++tag) sc[tag] = strans[tag] + em_l[tag];

    for (int t = 1; t < L_; ++t) {
      float ns[4];
#pragma unroll
      for (int to = 0; to < 4; ++to) {
        float best = sc[0] + tr[0][to];
        int bf = 0;
#pragma unroll
        for (int fr = 1; fr < 4; ++fr) {
          float v = sc[fr] + tr[fr][to];
          if (v > best) { best = v; bf = fr; }
        }
        ns[to] = best + em_l[t * 4 + to];
        hist_l[t * 4 + to] = bf;
      }
      const int mt = msk_l[t];
#pragma unroll
      for (int to = 0; to < 4; ++to) sc[to] = mt ? ns[to] : sc[to];
    }

#pragma unroll
    for (int tag = 0; tag < 4; ++tag) sc[tag] += etrans[tag];
    int cur = 0;
    float best = sc[0];
#pragma unroll
    for (int i = 1; i < 4; ++i)
      if (sc[i] > best) { best = sc[i]; cur = i; }

    tags_l[L_ - 1] = msk_l[L_ - 1] ? cur : 0;
    for (int t = L_ - 1; t >= 1; --t) {
      if (msk_l[t]) cur = hist_l[t * 4 + cur];
      tags_l[t - 1] = msk_l[t - 1] ? cur : 0;
    }
  }
  __syncthreads();
  for (int i = tid; i < 512; i += 64) out[b * L_ + i] = tags_l[i];
}

extern "C" void kernel_launch(void* const* d_in, const int* in_sizes, int n_in,
                              void* d_out, int out_size, void* d_ws, size_t ws_size,
                              hipStream_t stream) {
  const int*   word_ids = (const int*)d_in[0];
  const int*   mask     = (const int*)d_in[1];
  // d_in[2] label_ids: unused
  const float* emb   = (const float*)d_in[3];
  const float* Wih_f = (const float*)d_in[4];
  const float* Whh_f = (const float*)d_in[5];
  const float* b_f   = (const float*)d_in[6];
  const float* Wih_b = (const float*)d_in[7];
  const float* Whh_b = (const float*)d_in[8];
  const float* b_b   = (const float*)d_in[9];
  const float* W_out = (const float*)d_in[10];
  const float* b_out = (const float*)d_in[11];
  const float* trans = (const float*)d_in[12];
  const float* strans = (const float*)d_in[13];
  const float* etrans = (const float*)d_in[14];
  int* out = (int*)d_out;

  float* xg    = (float*)d_ws;                             // 128 MiB
  float* h_all = xg + (size_t)NTOK * XGLD;                 // 16*512*1024 f32 = 33.5 MB
  float* em    = h_all + (size_t)16 * L_ * 1024;           // 256 KiB

  const int n4 = 16 * L_ * 1024 / 4;                       // 2,097,152 f32x4
  fill_sentinel<<<(n4 + 255) / 256, 256, 0, stream>>>(h_all, n4);
  xproj_kernel<<<dim3(32, 256), 256, 0, stream>>>(word_ids, emb, Wih_f, Wih_b, b_f, b_b, xg);
  lstm_kernel<<<256, 512, 0, stream>>>(xg, Whh_f, Whh_b, h_all);
  emis_kernel<<<4096, 256, 0, stream>>>(h_all, W_out, b_out, em);
  viterbi_kernel<<<32, 64, 0, stream>>>(em, trans, strans, etrans, mask, out);
}